// Round 5
// baseline (194.179 us; speedup 1.0000x reference)
//
#include <hip/hip_runtime.h>
#include <hip/hip_fp16.h>

// Tree NN: reps = emb[tokens] (4096 x 128 x 128); 7x: reps = tanh(concat(pairs) @ W_tree^T + b);
// out = root @ W_cls^T + b_cls.
//
// R4b: same as R4 (software-pipelined embedding gather) with the pkrtz type fix
// (__builtin_amdgcn_cvt_pkrtz returns __fp16x2, bit_cast via auto).
//
// R3 counters (MfmaUtil 17, VALU 47, HBM 14%, occ 27%) showed ~60% of per-sample time is
// exposed latency (gather HBM latency + barrier drains). Sample s+1's 16 global_load_dwordx4
// are issued into registers BEFORE sample s's level loop; convert (v_cvt_pkrtz) + ds_write
// happen at the next loop top. Loads stay in flight across barriers. +64 VGPR (pf[16]);
// total ~150-165, under the 170 cap for 3 waves/SIMD (launch_bounds(256,3)).
// Also: clamp-free tanh (exp saturates correctly), packed fp32->fp16 converts.
//
// Wave w owns output n-tiles {2w,2w+1} at every level (Wf[2][8] = 64 VGPR of W-fragments).
// Activations in LDS, pair-contiguous so concat(left,right) is free.
// fp16 MFMA 16x16x32, fp32 accumulate, fp32 tanh, fp32 classifier.

typedef _Float16 half8 __attribute__((ext_vector_type(8)));
typedef float floatx4 __attribute__((ext_vector_type(4)));

#define STRIDE 264   // 256 + 8 fp16 pad (132 dwords, 33 uint4): A-row ds_read_b128 2-way (free)
#define NSAMP 4096

__device__ __forceinline__ float fast_tanh(float x) {
  // No clamp needed: e=inf -> 1-2*rcp(inf)=1; e=0 -> 1-2*rcp(1)=-1. Inputs never NaN.
  float e = __expf(2.f * x);
  return 1.f - 2.f * __builtin_amdgcn_rcpf(e + 1.f);
}

__device__ __forceinline__ unsigned pkrtz(float a, float b) {
  auto h = __builtin_amdgcn_cvt_pkrtz(a, b);   // __fp16 ext_vector(2)
  return __builtin_bit_cast(unsigned, h);
}

// One wave computes its 2 n-tiles for MT m-tiles of one level.
// A-frag: A[m=lane&15][k=quad*8+j]; B-frag: B[k=quad*8+j][n=lane&15];
// D: col=lane&15, row=quad*4+reg (verified layouts, learn_hip m89/m91).
template<int MT>
__device__ __forceinline__ void level_run(
    const _Float16* inb, _Float16* outb, float* rootbuf,
    const half8 (&Wf)[2][8], const float (&bias)[2],
    int Mout, bool writeRoot, int nbase, int l15, int quad)
{
  floatx4 acc[MT][2];
#pragma unroll
  for (int m = 0; m < MT; ++m) {
    acc[m][0] = (floatx4){0.f, 0.f, 0.f, 0.f};
    acc[m][1] = (floatx4){0.f, 0.f, 0.f, 0.f};
  }

#pragma unroll
  for (int m = 0; m < MT; ++m) {
    const _Float16* arow = inb + (m * 16 + l15) * STRIDE + quad * 8;
#pragma unroll
    for (int ks = 0; ks < 8; ++ks) {         // K = 256 = 8 steps of 32
      half8 a = *(const half8*)(arow + ks * 32);
      acc[m][0] = __builtin_amdgcn_mfma_f32_16x16x32_f16(a, Wf[0][ks], acc[m][0], 0, 0, 0);
      acc[m][1] = __builtin_amdgcn_mfma_f32_16x16x32_f16(a, Wf[1][ks], acc[m][1], 0, 0, 0);
    }
  }

  const int mrow = quad * 4;
#pragma unroll
  for (int m = 0; m < MT; ++m) {
#pragma unroll
    for (int i = 0; i < 2; ++i) {
      const int col = (nbase + i) * 16 + l15;  // output feature e
      const float b = bias[i];
#pragma unroll
      for (int r = 0; r < 4; ++r) {
        const int node = m * 16 + mrow + r;
        if (node < Mout) {                     // padded rows at deep levels: skip
          float v = fast_tanh(acc[m][i][r] + b);
          if (writeRoot) {
            rootbuf[col] = v;                  // Mout==1: only node 0 lands here, fp32
          } else {
            // pair-contiguous store: node j -> row j>>1, half j&1 (next level's A-matrix)
            outb[(node >> 1) * STRIDE + (node & 1) * 128 + col] = (_Float16)v;
          }
        }
      }
    }
  }
}

__global__ __launch_bounds__(256, 3)
void tree_kernel(const int* __restrict__ tokens,
                 const float* __restrict__ embedding,
                 const float* __restrict__ W_tree,
                 const float* __restrict__ b_tree,
                 const float* __restrict__ W_cls,
                 const float* __restrict__ b_cls,
                 float* __restrict__ out)
{
  __shared__ _Float16 bufA[64 * STRIDE];   // leaves / even-level outputs (33.8 KB)
  __shared__ _Float16 bufB[32 * STRIDE];   // odd-level outputs (16.9 KB)
  __shared__ float rootbuf[128];

  const int tid  = threadIdx.x;
  const int wid  = tid >> 6;
  const int lane = tid & 63;
  const int l15  = lane & 15;
  const int quad = lane >> 4;
  const int nbase = wid * 2;               // this wave's n-tile base (features [32*wid, 32*wid+32))

  // ---- stage this wave's 2 n-tiles of W_tree into registers as B-fragments ----
  // B[k][n] = W_tree[e=n][h=k]  (einsum 'bnh,eh->bne' => out = comb @ W^T)
  half8 Wf[2][8];                          // 64 VGPRs
#pragma unroll
  for (int i = 0; i < 2; ++i) {
    const int e = (nbase + i) * 16 + l15;
#pragma unroll
    for (int ks = 0; ks < 8; ++ks) {
      const int k = ks * 32 + quad * 8;
      const float4* p = (const float4*)(W_tree + e * 256 + k);
      float4 lo = p[0], hi = p[1];
      half8 f;
      f[0] = (_Float16)lo.x; f[1] = (_Float16)lo.y; f[2] = (_Float16)lo.z; f[3] = (_Float16)lo.w;
      f[4] = (_Float16)hi.x; f[5] = (_Float16)hi.y; f[6] = (_Float16)hi.z; f[7] = (_Float16)hi.w;
      Wf[i][ks] = f;
    }
  }
  float bias[2];
#pragma unroll
  for (int i = 0; i < 2; ++i) bias[i] = b_tree[(nbase + i) * 16 + l15];

  // ---- gather pipeline state: each thread owns 256B (half an embedding row) ----
  const int leaf = tid >> 1;               // 0..127
  const int hh   = tid & 1;                // which 64-float half of the row
  float4 pf[16];                           // 64 VGPRs in flight across the level loop

  // prologue: issue first sample's gather
  {
    const int tok = tokens[blockIdx.x * 128 + leaf];
    const float4* src = (const float4*)(embedding + (size_t)tok * 128 + hh * 64);
#pragma unroll
    for (int j = 0; j < 16; ++j) pf[j] = src[j];
  }

#pragma unroll 1
  for (int s = blockIdx.x; s < NSAMP; s += gridDim.x) {

    // ---- drain prefetch: fp32 -> fp16 packed, pair-contiguous ds_write_b128 into bufA ----
    {
      uint4* dst = (uint4*)bufA + (leaf >> 1) * 33 + (leaf & 1) * 16 + hh * 8;
#pragma unroll
      for (int j = 0; j < 8; ++j) {
        float4 x = pf[2 * j], y = pf[2 * j + 1];
        uint4 w;
        w.x = pkrtz(x.x, x.y); w.y = pkrtz(x.z, x.w);
        w.z = pkrtz(y.x, y.y); w.w = pkrtz(y.z, y.w);
        dst[j] = w;
      }
    }

    // ---- issue next sample's gather (lands during this sample's 7 levels) ----
    {
      int snext = s + gridDim.x;
      if (snext >= NSAMP) snext = s;       // harmless re-load on last iteration
      const int tok = tokens[snext * 128 + leaf];
      const float4* src = (const float4*)(embedding + (size_t)tok * 128 + hh * 64);
#pragma unroll
      for (int j = 0; j < 16; ++j) pf[j] = src[j];
    }
    __syncthreads();

    // ---- 7 tree levels (ping-pong bufA/bufB) ----
    // Mout = 64,32,16,8,4,2,1 ; MT = 4,2,1,1,1,1,1
    level_run<4>(bufA, bufB, rootbuf, Wf, bias, 64, false, nbase, l15, quad);
    __syncthreads();
    level_run<2>(bufB, bufA, rootbuf, Wf, bias, 32, false, nbase, l15, quad);
    __syncthreads();
    level_run<1>(bufA, bufB, rootbuf, Wf, bias, 16, false, nbase, l15, quad);
    __syncthreads();
    level_run<1>(bufB, bufA, rootbuf, Wf, bias,  8, false, nbase, l15, quad);
    __syncthreads();
    level_run<1>(bufA, bufB, rootbuf, Wf, bias,  4, false, nbase, l15, quad);
    __syncthreads();
    level_run<1>(bufB, bufA, rootbuf, Wf, bias,  2, false, nbase, l15, quad);
    __syncthreads();
    level_run<1>(bufA, bufB, rootbuf, Wf, bias,  1, true,  nbase, l15, quad);
    __syncthreads();

    // ---- classifier: wave 0, fp32, shuffle reduction ----
    if (wid == 0) {
      const float r0 = rootbuf[lane];
      const float r1 = rootbuf[lane + 64];
#pragma unroll
      for (int o = 0; o < 3; ++o) {
        float p = r0 * W_cls[o * 128 + lane] + r1 * W_cls[o * 128 + 64 + lane];
#pragma unroll
        for (int sh = 32; sh > 0; sh >>= 1) p += __shfl_down(p, sh, 64);
        if (lane == 0) out[s * 3 + o] = p + b_cls[o];
      }
    }
    // next iteration's ds_write to bufA is safe: last bufA reader (root level) is behind
    // the final barrier. classifier reads rootbuf, next written 7 barriers later.
  }
}

extern "C" void kernel_launch(void* const* d_in, const int* in_sizes, int n_in,
                              void* d_out, int out_size, void* d_ws, size_t ws_size,
                              hipStream_t stream) {
  const int*   tokens    = (const int*)d_in[0];
  const float* embedding = (const float*)d_in[1];
  const float* W_tree    = (const float*)d_in[2];
  const float* b_tree    = (const float*)d_in[3];
  const float* W_cls     = (const float*)d_in[4];
  const float* b_cls     = (const float*)d_in[5];
  float* out = (float*)d_out;

  dim3 grid(768), block(256);   // 3 blocks/CU x 256 CUs; grid-stride over 4096 samples
  tree_kernel<<<grid, block, 0, stream>>>(tokens, embedding, W_tree, b_tree, W_cls, b_cls, out);
}

// Round 6
// 189.593 us; speedup vs baseline: 1.0242x; 1.0242x over previous
//
#include <hip/hip_runtime.h>
#include <hip/hip_fp16.h>

// Tree NN: reps = emb[tokens] (4096 x 128 x 128); 7x: reps = tanh(concat(pairs) @ W_tree^T + b);
// out = root @ W_cls^T + b_cls.
//
// R6: fix R5's prefetch spill (WRITE_SIZE 0.17->47.5 MB scratch traffic, dispatch 112->124us).
// The fp32 pf[16] prefetch needed 64 VGPRs live across the level loop -> over the ~170 cap
// of launch_bounds(256,3). Fix: pre-convert the embedding table to fp16 ONCE per launch
// (25.6 MB into d_ws, ~15us kernel), so the per-sample gather prefetch is 8 x uint4 = 32 VGPR.
// Drain is then 8 raw ds_write_b128 (no pkrtz in the hot loop); gather bytes halve.
// Fallback (ws too small): compile-time fp32 path, R3-style non-prefetch gather.
//
// Wave w owns output n-tiles {2w,2w+1} at every level (Wf[2][8] = 64 VGPR of W-fragments).
// Activations in LDS, pair-contiguous so concat(left,right) is free.
// fp16 MFMA 16x16x32, fp32 accumulate, fp32 tanh, fp32 classifier.

typedef _Float16 half8 __attribute__((ext_vector_type(8)));
typedef float floatx4 __attribute__((ext_vector_type(4)));

#define STRIDE 264   // 256 + 8 fp16 pad (132 dwords, 33 uint4): A-row ds_read_b128 2-way (free)
#define NSAMP 4096
#define EMB_ELEMS (100000 * 128)

__device__ __forceinline__ float fast_tanh(float x) {
  // No clamp needed: e=inf -> 1-2*rcp(inf)=1; e=0 -> 1-2*rcp(1)=-1. Inputs never NaN.
  float e = __expf(2.f * x);
  return 1.f - 2.f * __builtin_amdgcn_rcpf(e + 1.f);
}

__device__ __forceinline__ unsigned pkrtz(float a, float b) {
  auto h = __builtin_amdgcn_cvt_pkrtz(a, b);   // __fp16 ext_vector(2)
  return __builtin_bit_cast(unsigned, h);
}

// ---- embedding fp32 -> fp16 pre-pass (once per launch; ~77 MB traffic ~ 15 us) ----
__global__ __launch_bounds__(256) void convert_emb(const float* __restrict__ emb,
                                                   _Float16* __restrict__ emb16, int n8) {
  int i = blockIdx.x * 256 + threadIdx.x;      // one thread per 8 elements
  if (i < n8) {
    float4 a = ((const float4*)emb)[2 * i];
    float4 b = ((const float4*)emb)[2 * i + 1];
    uint4 w;
    w.x = pkrtz(a.x, a.y); w.y = pkrtz(a.z, a.w);
    w.z = pkrtz(b.x, b.y); w.w = pkrtz(b.z, b.w);
    ((uint4*)emb16)[i] = w;
  }
}

// One wave computes its 2 n-tiles for MT m-tiles of one level.
// A-frag: A[m=lane&15][k=quad*8+j]; B-frag: B[k=quad*8+j][n=lane&15];
// D: col=lane&15, row=quad*4+reg (verified layouts, learn_hip m89/m91).
template<int MT>
__device__ __forceinline__ void level_run(
    const _Float16* inb, _Float16* outb, float* rootbuf,
    const half8 (&Wf)[2][8], const float (&bias)[2],
    int Mout, bool writeRoot, int nbase, int l15, int quad)
{
  floatx4 acc[MT][2];
#pragma unroll
  for (int m = 0; m < MT; ++m) {
    acc[m][0] = (floatx4){0.f, 0.f, 0.f, 0.f};
    acc[m][1] = (floatx4){0.f, 0.f, 0.f, 0.f};
  }

#pragma unroll
  for (int m = 0; m < MT; ++m) {
    const _Float16* arow = inb + (m * 16 + l15) * STRIDE + quad * 8;
#pragma unroll
    for (int ks = 0; ks < 8; ++ks) {         // K = 256 = 8 steps of 32
      half8 a = *(const half8*)(arow + ks * 32);
      acc[m][0] = __builtin_amdgcn_mfma_f32_16x16x32_f16(a, Wf[0][ks], acc[m][0], 0, 0, 0);
      acc[m][1] = __builtin_amdgcn_mfma_f32_16x16x32_f16(a, Wf[1][ks], acc[m][1], 0, 0, 0);
    }
  }

  const int mrow = quad * 4;
#pragma unroll
  for (int m = 0; m < MT; ++m) {
#pragma unroll
    for (int i = 0; i < 2; ++i) {
      const int col = (nbase + i) * 16 + l15;  // output feature e
      const float b = bias[i];
#pragma unroll
      for (int r = 0; r < 4; ++r) {
        const int node = m * 16 + mrow + r;
        if (node < Mout) {                     // padded rows at deep levels: skip
          float v = fast_tanh(acc[m][i][r] + b);
          if (writeRoot) {
            rootbuf[col] = v;                  // Mout==1: only node 0 lands here, fp32
          } else {
            // pair-contiguous store: node j -> row j>>1, half j&1 (next level's A-matrix)
            outb[(node >> 1) * STRIDE + (node & 1) * 128 + col] = (_Float16)v;
          }
        }
      }
    }
  }
}

template<bool F16>
__global__ __launch_bounds__(256, 3)
void tree_kernel(const int* __restrict__ tokens,
                 const float* __restrict__ embedding,
                 const _Float16* __restrict__ emb16,
                 const float* __restrict__ W_tree,
                 const float* __restrict__ b_tree,
                 const float* __restrict__ W_cls,
                 const float* __restrict__ b_cls,
                 float* __restrict__ out)
{
  __shared__ _Float16 bufA[64 * STRIDE];   // leaves / even-level outputs (33.8 KB)
  __shared__ _Float16 bufB[32 * STRIDE];   // odd-level outputs (16.9 KB)
  __shared__ float rootbuf[128];

  const int tid  = threadIdx.x;
  const int wid  = tid >> 6;
  const int lane = tid & 63;
  const int l15  = lane & 15;
  const int quad = lane >> 4;
  const int nbase = wid * 2;               // this wave's n-tile base (features [32*wid, 32*wid+32))

  // ---- stage this wave's 2 n-tiles of W_tree into registers as B-fragments ----
  // B[k][n] = W_tree[e=n][h=k]  (einsum 'bnh,eh->bne' => out = comb @ W^T)
  half8 Wf[2][8];                          // 64 VGPRs
#pragma unroll
  for (int i = 0; i < 2; ++i) {
    const int e = (nbase + i) * 16 + l15;
#pragma unroll
    for (int ks = 0; ks < 8; ++ks) {
      const int k = ks * 32 + quad * 8;
      const float4* p = (const float4*)(W_tree + e * 256 + k);
      float4 lo = p[0], hi = p[1];
      half8 f;
      f[0] = (_Float16)lo.x; f[1] = (_Float16)lo.y; f[2] = (_Float16)lo.z; f[3] = (_Float16)lo.w;
      f[4] = (_Float16)hi.x; f[5] = (_Float16)hi.y; f[6] = (_Float16)hi.z; f[7] = (_Float16)hi.w;
      Wf[i][ks] = f;
    }
  }
  float bias[2];
#pragma unroll
  for (int i = 0; i < 2; ++i) bias[i] = b_tree[(nbase + i) * 16 + l15];

  // classifier weights: loop-invariant, hoisted (wave 0 only uses them)
  float wc0[3], wc1[3], bc[3];
#pragma unroll
  for (int o = 0; o < 3; ++o) {
    wc0[o] = W_cls[o * 128 + lane];
    wc1[o] = W_cls[o * 128 + 64 + lane];
    bc[o]  = b_cls[o];
  }

  // ---- gather pipeline state: each thread owns half an embedding row ----
  const int leaf = tid >> 1;               // 0..127
  const int hh   = tid & 1;                // which 64-feature half of the row
  uint4 pf[8];                             // fp16 prefetch: 32 VGPRs in flight across levels

  if (F16) {                               // prologue: issue first sample's gather
    const int tok = tokens[blockIdx.x * 128 + leaf];
    const uint4* src = (const uint4*)(emb16 + (size_t)tok * 128 + hh * 64);
#pragma unroll
    for (int j = 0; j < 8; ++j) pf[j] = src[j];
  }

#pragma unroll 1
  for (int s = blockIdx.x; s < NSAMP; s += gridDim.x) {

    uint4* dst = (uint4*)bufA + (leaf >> 1) * 33 + (leaf & 1) * 16 + hh * 8;
    if (F16) {
      // ---- drain prefetch: raw ds_write_b128, pair-contiguous into bufA ----
#pragma unroll
      for (int j = 0; j < 8; ++j) dst[j] = pf[j];
      // ---- issue next sample's gather (lands during this sample's 7 levels) ----
      int snext = s + gridDim.x;
      if (snext >= NSAMP) snext = s;       // harmless re-load on last iteration
      const int tok = tokens[snext * 128 + leaf];
      const uint4* src = (const uint4*)(emb16 + (size_t)tok * 128 + hh * 64);
#pragma unroll
      for (int j = 0; j < 8; ++j) pf[j] = src[j];
    } else {
      // fallback: direct fp32 gather + convert (R3 style, no prefetch)
      const int tok = tokens[s * 128 + leaf];
      const float4* src = (const float4*)(embedding + (size_t)tok * 128 + hh * 64);
#pragma unroll
      for (int j = 0; j < 8; ++j) {
        float4 x = src[2 * j], y = src[2 * j + 1];
        uint4 w;
        w.x = pkrtz(x.x, x.y); w.y = pkrtz(x.z, x.w);
        w.z = pkrtz(y.x, y.y); w.w = pkrtz(y.z, y.w);
        dst[j] = w;
      }
    }
    __syncthreads();

    // ---- 7 tree levels (ping-pong bufA/bufB) ----
    // Mout = 64,32,16,8,4,2,1 ; MT = 4,2,1,1,1,1,1
    level_run<4>(bufA, bufB, rootbuf, Wf, bias, 64, false, nbase, l15, quad);
    __syncthreads();
    level_run<2>(bufB, bufA, rootbuf, Wf, bias, 32, false, nbase, l15, quad);
    __syncthreads();
    level_run<1>(bufA, bufB, rootbuf, Wf, bias, 16, false, nbase, l15, quad);
    __syncthreads();
    level_run<1>(bufB, bufA, rootbuf, Wf, bias,  8, false, nbase, l15, quad);
    __syncthreads();
    level_run<1>(bufA, bufB, rootbuf, Wf, bias,  4, false, nbase, l15, quad);
    __syncthreads();
    level_run<1>(bufB, bufA, rootbuf, Wf, bias,  2, false, nbase, l15, quad);
    __syncthreads();
    level_run<1>(bufA, bufB, rootbuf, Wf, bias,  1, true,  nbase, l15, quad);
    __syncthreads();

    // ---- classifier: wave 0, fp32, shuffle reduction ----
    if (wid == 0) {
      const float r0 = rootbuf[lane];
      const float r1 = rootbuf[lane + 64];
#pragma unroll
      for (int o = 0; o < 3; ++o) {
        float p = r0 * wc0[o] + r1 * wc1[o];
#pragma unroll
        for (int sh = 32; sh > 0; sh >>= 1) p += __shfl_down(p, sh, 64);
        if (lane == 0) out[s * 3 + o] = p + bc[o];
      }
    }
    // next iteration's ds_write to bufA is safe: last bufA reader (root level) is behind
    // the final barrier. classifier reads rootbuf, next written 7 barriers later.
  }
}

extern "C" void kernel_launch(void* const* d_in, const int* in_sizes, int n_in,
                              void* d_out, int out_size, void* d_ws, size_t ws_size,
                              hipStream_t stream) {
  const int*   tokens    = (const int*)d_in[0];
  const float* embedding = (const float*)d_in[1];
  const float* W_tree    = (const float*)d_in[2];
  const float* b_tree    = (const float*)d_in[3];
  const float* W_cls     = (const float*)d_in[4];
  const float* b_cls     = (const float*)d_in[5];
  float* out = (float*)d_out;

  const size_t need = (size_t)EMB_ELEMS * sizeof(_Float16);  // 25.6 MB
  if (ws_size >= need) {
    _Float16* emb16 = (_Float16*)d_ws;
    const int n8 = EMB_ELEMS / 8;                            // 1.6M
    convert_emb<<<dim3((n8 + 255) / 256), dim3(256), 0, stream>>>(embedding, emb16, n8);
    tree_kernel<true><<<dim3(768), dim3(256), 0, stream>>>(
        tokens, embedding, emb16, W_tree, b_tree, W_cls, b_cls, out);
  } else {
    tree_kernel<false><<<dim3(768), dim3(256), 0, stream>>>(
        tokens, embedding, nullptr, W_tree, b_tree, W_cls, b_cls, out);
  }
}